// Round 2
// baseline (120.107 us; speedup 1.0000x reference)
//
#include <hip/hip_runtime.h>

// Problem constants: zs is (V=2, B=8192, F=4096) fp32. N = V*B = 16384 rows,
// F = 4096 features on the contiguous axis. Per-feature column reductions.
constexpr int F_DIM = 4096;
constexpr int TPB = 256;
constexpr int FEAT_PER_BLOCK = TPB * 4;   // each thread owns 4 consecutive features (float4)

// Pass 1: streaming raw-moment partial sums.
// grid = (F/1024 feature-chunks, NCHUNK row-chunks). Each thread reads one
// float4 (4 features) per row, rows_per_chunk rows, accumulating S1..S4 in
// fp32 registers. Writes float4{S1,S2,S3,S4} per (chunk, feature) to ws.
__global__ void __launch_bounds__(TPB) cov_pass1(
    const float* __restrict__ zs, float4* __restrict__ part, int rows_per_chunk) {
  const int f4 = blockIdx.x * TPB + threadIdx.x;         // float4 column index
  const int chunk = blockIdx.y;
  const size_t row0 = (size_t)chunk * rows_per_chunk;
  const float4* __restrict__ src =
      reinterpret_cast<const float4*>(zs) + row0 * (F_DIM / 4) + f4;

  float s1[4] = {0.f, 0.f, 0.f, 0.f};
  float s2[4] = {0.f, 0.f, 0.f, 0.f};
  float s3[4] = {0.f, 0.f, 0.f, 0.f};
  float s4[4] = {0.f, 0.f, 0.f, 0.f};

  for (int r = 0; r < rows_per_chunk; ++r) {
    float4 z = src[(size_t)r * (F_DIM / 4)];
    float v[4] = {z.x, z.y, z.z, z.w};
#pragma unroll
    for (int j = 0; j < 4; ++j) {
      float x = v[j];
      float x2 = x * x;
      s1[j] += x;
      s2[j] = fmaf(x, x, s2[j]);
      s3[j] = fmaf(x2, x, s3[j]);
      s4[j] = fmaf(x2, x2, s4[j]);
    }
  }

  float4* dst = part + (size_t)chunk * F_DIM + (size_t)f4 * 4;
#pragma unroll
  for (int j = 0; j < 4; ++j)
    dst[j] = make_float4(s1[j], s2[j], s3[j], s4[j]);
}

// Pass 2: per-feature fp64 combine across chunks + centered-moment algebra +
// per-block reduction of loss_f. One thread per feature; F/TPB blocks.
__global__ void __launch_bounds__(TPB) cov_pass2(
    const float4* __restrict__ part, double* __restrict__ blk, int nchunk, int N) {
  const int f = blockIdx.x * TPB + threadIdx.x;
  double S1 = 0.0, S2 = 0.0, S3 = 0.0, S4 = 0.0;
  for (int c = 0; c < nchunk; ++c) {
    float4 p = part[(size_t)c * F_DIM + f];
    S1 += (double)p.x;
    S2 += (double)p.y;
    S3 += (double)p.z;
    S4 += (double)p.w;
  }
  const double n = (double)N;
  const double m = S1 / n;
  const double m2 = m * m;
  const double s2c = S2 - n * m2;                                   // sum (z-m)^2
  const double s4c = S4 - 4.0 * m * S3 + 6.0 * m2 * S2 - 3.0 * n * m2 * m2;  // sum (z-m)^4
  double loss = s2c * s2c - s4c;   // numerator of loss_f (scale applied in pass 3)

  __shared__ double red[TPB];
  red[threadIdx.x] = loss;
  __syncthreads();
  for (int s = TPB / 2; s > 0; s >>= 1) {
    if (threadIdx.x < s) red[threadIdx.x] += red[threadIdx.x + s];
    __syncthreads();
  }
  if (threadIdx.x == 0) blk[blockIdx.x] = red[0];
}

// Pass 3: tiny deterministic final reduction + scaling.
__global__ void cov_pass3(const double* __restrict__ blk, int nblk, int N,
                          float* __restrict__ out) {
  if (threadIdx.x == 0 && blockIdx.x == 0) {
    double s = 0.0;
    for (int i = 0; i < nblk; ++i) s += blk[i];
    const double nm1 = (double)(N - 1);
    out[0] = (float)(s / (nm1 * nm1 * nm1 * (double)F_DIM));
  }
}

extern "C" void kernel_launch(void* const* d_in, const int* in_sizes, int n_in,
                              void* d_out, int out_size, void* d_ws, size_t ws_size,
                              hipStream_t stream) {
  const float* zs = (const float*)d_in[0];
  float* out = (float*)d_out;
  const size_t total = (size_t)in_sizes[0];
  const int N = (int)(total / F_DIM);   // 16384 rows (V*B)

  // Pick the row-chunk count that fits the workspace (defensive: shrink if
  // ws_size is small). Partial buffer = nchunk * F * sizeof(float4).
  int nchunk = 256;
  while (nchunk > 1 &&
         ((size_t)nchunk * F_DIM * sizeof(float4) + 4096 > ws_size ||
          (N % nchunk) != 0)) {
    nchunk >>= 1;
  }
  const int rows_per_chunk = N / nchunk;

  float4* part = (float4*)d_ws;
  double* blk = (double*)((char*)d_ws + (size_t)nchunk * F_DIM * sizeof(float4));

  dim3 g1(F_DIM / FEAT_PER_BLOCK, nchunk);   // (4, 256) = 1024 blocks
  cov_pass1<<<g1, TPB, 0, stream>>>(zs, part, rows_per_chunk);

  const int nblk2 = F_DIM / TPB;             // 16 blocks
  cov_pass2<<<nblk2, TPB, 0, stream>>>(part, blk, nchunk, N);

  cov_pass3<<<1, 64, 0, stream>>>(blk, nblk2, N, out);
}

// Round 3
// 59.065 us; speedup vs baseline: 2.0335x; 2.0335x over previous
//
#include <hip/hip_runtime.h>

// zs: (V=2, B=8192, F=4096) fp32 row-major -> N = 16384 rows, F = 4096 contiguous.
// loss = mean_f[ (s2c^2 - s4c) / (N-1)^3 ] via raw moments S1..S4 per feature.
constexpr int F_DIM = 4096;
constexpr int TPB = 256;
constexpr int FEAT_PER_BLOCK = TPB * 4;   // each thread owns one float4 (4 features)

// ---------------- Pass 1: streaming raw-moment partials ----------------
// grid = (F/1024, nchunk). Each thread reads one float4 per row for
// rows_per_chunk rows; 4-row unroll keeps 4 dwordx4 loads in flight.
__global__ void __launch_bounds__(TPB) cov_pass1(
    const float* __restrict__ zs, float4* __restrict__ part, int rows_per_chunk) {
  const int f4 = blockIdx.x * TPB + threadIdx.x;         // float4 column index
  const int chunk = blockIdx.y;
  const size_t row0 = (size_t)chunk * rows_per_chunk;
  const float4* __restrict__ src =
      reinterpret_cast<const float4*>(zs) + row0 * (F_DIM / 4) + f4;
  const size_t rstride = F_DIM / 4;

  float s1[4] = {0.f, 0.f, 0.f, 0.f};
  float s2[4] = {0.f, 0.f, 0.f, 0.f};
  float s3[4] = {0.f, 0.f, 0.f, 0.f};
  float s4[4] = {0.f, 0.f, 0.f, 0.f};

  int r = 0;
  for (; r + 4 <= rows_per_chunk; r += 4) {
    float4 z0 = src[(size_t)(r + 0) * rstride];
    float4 z1 = src[(size_t)(r + 1) * rstride];
    float4 z2 = src[(size_t)(r + 2) * rstride];
    float4 z3 = src[(size_t)(r + 3) * rstride];
    float4 zz[4] = {z0, z1, z2, z3};
#pragma unroll
    for (int u = 0; u < 4; ++u) {
      float v[4] = {zz[u].x, zz[u].y, zz[u].z, zz[u].w};
#pragma unroll
      for (int j = 0; j < 4; ++j) {
        float x = v[j];
        float x2 = x * x;
        s1[j] += x;
        s2[j] = fmaf(x, x, s2[j]);
        s3[j] = fmaf(x2, x, s3[j]);
        s4[j] = fmaf(x2, x2, s4[j]);
      }
    }
  }
  for (; r < rows_per_chunk; ++r) {          // tail (unused for pow2 sizes)
    float4 z = src[(size_t)r * rstride];
    float v[4] = {z.x, z.y, z.z, z.w};
#pragma unroll
    for (int j = 0; j < 4; ++j) {
      float x = v[j];
      float x2 = x * x;
      s1[j] += x;
      s2[j] = fmaf(x, x, s2[j]);
      s3[j] = fmaf(x2, x, s3[j]);
      s4[j] = fmaf(x2, x2, s4[j]);
    }
  }

  float4* dst = part + (size_t)chunk * F_DIM + (size_t)f4 * 4;
#pragma unroll
  for (int j = 0; j < 4; ++j)
    dst[j] = make_float4(s1[j], s2[j], s3[j], s4[j]);
}

// ---------------- Pass 2: fp64 combine + loss, 256 blocks ----------------
// Block b owns features [b*16, b*16+16). Thread t: fi = t&15 (feature),
// ci = t>>4 (chunk lane, 16 lanes per feature). Consecutive lanes read
// consecutive features -> coalesced 256B segments.
__global__ void __launch_bounds__(TPB) cov_pass2(
    const float4* __restrict__ part, double* __restrict__ blk, int nchunk, int N) {
  const int fi = threadIdx.x & 15;
  const int ci = threadIdx.x >> 4;
  const int f = blockIdx.x * 16 + fi;

  double S[4] = {0.0, 0.0, 0.0, 0.0};
  for (int c = ci; c < nchunk; c += 16) {
    float4 p = part[(size_t)c * F_DIM + f];
    S[0] += (double)p.x;
    S[1] += (double)p.y;
    S[2] += (double)p.z;
    S[3] += (double)p.w;
  }

  __shared__ double red[16][16][4];
#pragma unroll
  for (int m = 0; m < 4; ++m) red[ci][fi][m] = S[m];
  __syncthreads();

  __shared__ double loss_lds[16];
  if (threadIdx.x < 16) {                    // one thread per feature
    const int ff = threadIdx.x;
    double S1 = 0.0, S2 = 0.0, S3 = 0.0, S4 = 0.0;
    for (int c = 0; c < 16; ++c) {
      S1 += red[c][ff][0];
      S2 += red[c][ff][1];
      S3 += red[c][ff][2];
      S4 += red[c][ff][3];
    }
    const double n = (double)N;
    const double m = S1 / n;
    const double m2 = m * m;
    const double s2c = S2 - n * m2;
    const double s4c = S4 - 4.0 * m * S3 + 6.0 * m2 * S2 - 3.0 * n * m2 * m2;
    loss_lds[ff] = s2c * s2c - s4c;
  }
  __syncthreads();
  if (threadIdx.x == 0) {
    double s = 0.0;
    for (int i = 0; i < 16; ++i) s += loss_lds[i];
    blk[blockIdx.x] = s;
  }
}

// ---------------- Pass 3: final 256-wide reduce + scale ----------------
__global__ void __launch_bounds__(TPB) cov_pass3(
    const double* __restrict__ blk, int nblk, double scale, float* __restrict__ out) {
  __shared__ double red[TPB];
  double v = (threadIdx.x < nblk) ? blk[threadIdx.x] : 0.0;
  // fold in any blocks beyond TPB (defensive; nblk == 256 normally)
  for (int i = threadIdx.x + TPB; i < nblk; i += TPB) v += blk[i];
  red[threadIdx.x] = v;
  __syncthreads();
  for (int s = TPB / 2; s > 0; s >>= 1) {
    if (threadIdx.x < s) red[threadIdx.x] += red[threadIdx.x + s];
    __syncthreads();
  }
  if (threadIdx.x == 0) out[0] = (float)(red[0] * scale);
}

extern "C" void kernel_launch(void* const* d_in, const int* in_sizes, int n_in,
                              void* d_out, int out_size, void* d_ws, size_t ws_size,
                              hipStream_t stream) {
  const float* zs = (const float*)d_in[0];
  float* out = (float*)d_out;
  const size_t total = (size_t)in_sizes[0];
  const int N = (int)(total / F_DIM);        // 16384 rows

  int nchunk = 256;                           // partials = nchunk*F*16B = 16 MB
  while (nchunk > 1 &&
         ((size_t)nchunk * F_DIM * sizeof(float4) + 8192 > ws_size ||
          (N % nchunk) != 0)) {
    nchunk >>= 1;
  }
  const int rows_per_chunk = N / nchunk;

  float4* part = (float4*)d_ws;
  double* blk = (double*)((char*)d_ws + (size_t)nchunk * F_DIM * sizeof(float4));

  dim3 g1(F_DIM / FEAT_PER_BLOCK, nchunk);    // (4, 256) = 1024 blocks
  cov_pass1<<<g1, TPB, 0, stream>>>(zs, part, rows_per_chunk);

  const int nblk2 = F_DIM / 16;               // 256 blocks
  cov_pass2<<<nblk2, TPB, 0, stream>>>(part, blk, nchunk, N);

  const double nm1 = (double)(N - 1);
  const double scale = 1.0 / (nm1 * nm1 * nm1 * (double)F_DIM);
  cov_pass3<<<1, TPB, 0, stream>>>(blk, nblk2, scale, out);
}